// Round 6
// baseline (294.691 us; speedup 1.0000x reference)
//
#include <hip/hip_runtime.h>
#include <hip/hip_cooperative_groups.h>
#include <math.h>

namespace cg = cooperative_groups;

// Problem constants
#define NB   256   // batch
#define NIN  1024  // in_features
#define NOUT 1024  // out_features
#define NSF  128   // sub_features (rank)
#define NQ   1024  // q_features
#define NS   64    // num subnets
#define NACT 8     // top-k active
#define NSLOT 64   // per-subnet slot capacity (nb ~ Binom(256,~1/8): max ~50)
#define NBLK 256   // persistent grid: 1 block/CU — coop co-residency always OK

// Workspace layout (bytes). Total ~16.8 MB.
#define WS_COUNTS 0          // 64 ints (host memset)
#define WS_LISTBK 1024       // int  [64][64]
#define WS_LISTW  17408      // float[64][64]
#define WS_Y      33792      // float[2048][1024] Ybuf[b*8+k][o]            (8.39 MB)
#define WS_H      8422400    // float[4][64][64][128] Hpart[ic][s][slot][r] (8.39 MB)

// ===========================================================================
// Fused cooperative kernel: attn -> B1 -> B2 -> reduce with grid.sync().
// 256 blocks x 256 threads. LDS union ~42 KB.
// ===========================================================================
__global__ __launch_bounds__(256) void fused_all(
    const float* __restrict__ x, const float* __restrict__ q,
    const float* __restrict__ Wk, const float* __restrict__ bk,
    const float* __restrict__ V0, const float* __restrict__ V1,
    int* __restrict__ counts, int* __restrict__ list_bk,
    float* __restrict__ list_w, float* __restrict__ Ybuf,
    float* __restrict__ Hpart, float* __restrict__ out)
{
    cg::grid_group grid = cg::this_grid();
    const int blk = blockIdx.x;
    const int t   = threadIdx.x;

    __shared__ union SMem {
        struct { float qs[NQ]; float att[NS]; } a;
        struct { float v0t[64][129]; float xt[64][33]; int bidx[32]; } p1;
        struct { float v1t[64][129]; float hs[64][33]; int bkx[32]; float wjs[32]; } p2;
    } sm;

    // ---- Phase A: attention + top-8 + softmax + append (1 row per block) ---
    {
        ((float4*)sm.a.qs)[t] = ((const float4*)(q + (size_t)blk * NQ))[t];
        __syncthreads();
        int sid = t >> 2, il = t & 3;
        const float* wrow = Wk + (size_t)sid * NQ + (il << 2);
        const float* qrow = sm.a.qs + (il << 2);
        float acc = 0.f;
        #pragma unroll 8
        for (int i = 0; i < NQ; i += 16) {
            float4 w4 = *(const float4*)(wrow + i);
            float4 q4 = *(const float4*)(qrow + i);
            acc += w4.x * q4.x + w4.y * q4.y + w4.z * q4.z + w4.w * q4.w;
        }
        acc += __shfl_xor(acc, 1);
        acc += __shfl_xor(acc, 2);
        if (il == 0) sm.a.att[sid] = acc + bk[sid];
        __syncthreads();

        if (t < 64) {
            float v = sm.a.att[t];
            float top_v[NACT]; int top_i[NACT];
            #pragma unroll
            for (int k = 0; k < NACT; ++k) {
                float mv = v; int mi = t;
                #pragma unroll
                for (int off = 1; off < 64; off <<= 1) {
                    float ov = __shfl_xor(mv, off);
                    int   oi = __shfl_xor(mi, off);
                    if (ov > mv || (ov == mv && oi < mi)) { mv = ov; mi = oi; }
                }
                top_v[k] = mv; top_i[k] = mi;
                if (t == mi) v = -INFINITY;
            }
            if (t == 0) {
                float m = top_v[0], den = 0.f, e[NACT];
                #pragma unroll
                for (int k = 0; k < NACT; ++k) { e[k] = expf(top_v[k] - m); den += e[k]; }
                float inv = 1.f / den;
                #pragma unroll
                for (int k = 0; k < NACT; ++k) {
                    int s = top_i[k];
                    int slot = atomicAdd(&counts[s], 1);
                    if (slot < NSLOT) {
                        list_bk[s * NSLOT + slot] = blk * NACT + k;
                        list_w[s * NSLOT + slot]  = e[k] * inv;
                    }
                }
            }
        }
    }
    grid.sync();

    // ---- Phase B1: Hpart[ic][s][j][r] = V0[s,r,ic*256:+256] . x[b_j] -------
    // 512 tiles (s, ic in 4, jt in 2), grid-stride 2 per block.
    for (int vt = blk; vt < NS * 4 * 2; vt += NBLK) {
        int s  = vt & 63;
        int ic = (vt >> 6) & 3;
        int jt = vt >> 8;
        int nb = counts[s]; if (nb > NSLOT) nb = NSLOT;
        if (jt * 32 >= nb) continue;

        __syncthreads();   // protect LDS reuse across tiles
        if (t < 32) {
            int idx = jt * 32 + t;
            sm.p1.bidx[t] = (idx < nb) ? (list_bk[s * NSLOT + idx] >> 3) : 0;
        }
        __syncthreads();

        int i0 = ic * 256;
        const float* V0s = V0 + (size_t)s * NSF * NIN + i0;

        int lr  = t >> 4;            // 0..15
        int li4 = (t & 15) << 2;     // 0..60 (i within 64-sub-chunk)
        int to4 = (t & 31) << 2;     // r-offset 0..124
        int tj4 = (t >> 5) << 2;     // j-offset 0..28

        float4 va[8], vb[2];
        float acc[4][4] = {};

        #pragma unroll
        for (int rep = 0; rep < 8; ++rep)
            va[rep] = *(const float4*)(V0s + (size_t)(rep * 16 + lr) * NIN + li4);
        #pragma unroll
        for (int rep = 0; rep < 2; ++rep)
            vb[rep] = *(const float4*)(x + (size_t)sm.p1.bidx[rep * 16 + lr] * NIN + i0 + li4);

        for (int ks = 0; ks < 256; ks += 64) {
            #pragma unroll
            for (int rep = 0; rep < 8; ++rep) {
                int r = rep * 16 + lr;
                sm.p1.v0t[li4 + 0][r] = va[rep].x; sm.p1.v0t[li4 + 1][r] = va[rep].y;
                sm.p1.v0t[li4 + 2][r] = va[rep].z; sm.p1.v0t[li4 + 3][r] = va[rep].w;
            }
            #pragma unroll
            for (int rep = 0; rep < 2; ++rep) {
                int j = rep * 16 + lr;
                sm.p1.xt[li4 + 0][j] = vb[rep].x; sm.p1.xt[li4 + 1][j] = vb[rep].y;
                sm.p1.xt[li4 + 2][j] = vb[rep].z; sm.p1.xt[li4 + 3][j] = vb[rep].w;
            }
            __syncthreads();
            if (ks < 192) {
                int kn = ks + 64;
                #pragma unroll
                for (int rep = 0; rep < 8; ++rep)
                    va[rep] = *(const float4*)(V0s + (size_t)(rep * 16 + lr) * NIN + kn + li4);
                #pragma unroll
                for (int rep = 0; rep < 2; ++rep)
                    vb[rep] = *(const float4*)(x + (size_t)sm.p1.bidx[rep * 16 + lr] * NIN + i0 + kn + li4);
            }
            #pragma unroll 8
            for (int i = 0; i < 64; ++i) {
                float4 a = *(const float4*)&sm.p1.v0t[i][to4];
                float4 h = *(const float4*)&sm.p1.xt[i][tj4];
                acc[0][0] += a.x * h.x; acc[0][1] += a.x * h.y; acc[0][2] += a.x * h.z; acc[0][3] += a.x * h.w;
                acc[1][0] += a.y * h.x; acc[1][1] += a.y * h.y; acc[1][2] += a.y * h.z; acc[1][3] += a.y * h.w;
                acc[2][0] += a.z * h.x; acc[2][1] += a.z * h.y; acc[2][2] += a.z * h.z; acc[2][3] += a.z * h.w;
                acc[3][0] += a.w * h.x; acc[3][1] += a.w * h.y; acc[3][2] += a.w * h.z; acc[3][3] += a.w * h.w;
            }
            __syncthreads();
        }

        float* Hp = Hpart + ((size_t)(ic * NS + s) * NSLOT + jt * 32) * NSF;
        #pragma unroll
        for (int ji = 0; ji < 4; ++ji) {
            *(float4*)(Hp + (size_t)(tj4 + ji) * NSF + to4) =
                make_float4(acc[0][ji], acc[1][ji], acc[2][ji], acc[3][ji]);
        }
    }
    grid.sync();

    // ---- Phase B2: Y = V1 . (sum_ic Hpart); Ybuf[bk_j][o] = w_j * Y --------
    // 1024 tiles (s, ot in 8, jt in 2), grid-stride 4 per block.
    {
        const size_t HSTRIDE = (size_t)NS * NSLOT * NSF;
        for (int vt = blk; vt < NS * 8 * 2; vt += NBLK) {
            int s  = vt & 63;
            int ot = (vt >> 6) & 7;
            int jt = vt >> 9;
            int nb = counts[s]; if (nb > NSLOT) nb = NSLOT;
            if (jt * 32 >= nb) continue;

            __syncthreads();
            if (t < 32) {
                int idx = jt * 32 + t;
                bool val = idx < nb;
                sm.p2.bkx[t] = val ? list_bk[s * NSLOT + idx] : 0;
                sm.p2.wjs[t] = val ? list_w[s * NSLOT + idx] : 0.f;
            }

            const float* V1s = V1 + (size_t)s * NOUT * NSF + (size_t)ot * 128 * NSF;
            const float* Hp  = Hpart + ((size_t)s * NSLOT + jt * 32) * NSF;

            int lr  = t >> 4;
            int r4  = (t & 15) << 2;
            int to4 = (t & 31) << 2;
            int tj4 = (t >> 5) << 2;

            float4 wa[8], ha[2];
            float acc[4][4] = {};

            #pragma unroll
            for (int rep = 0; rep < 8; ++rep)
                wa[rep] = *(const float4*)(V1s + (size_t)(rep * 16 + lr) * NSF + r4);
            #pragma unroll
            for (int rep = 0; rep < 2; ++rep) {
                const float* hp = Hp + (size_t)(rep * 16 + lr) * NSF + r4;
                float4 u0 = *(const float4*)(hp);
                float4 u1 = *(const float4*)(hp + HSTRIDE);
                float4 u2 = *(const float4*)(hp + 2 * HSTRIDE);
                float4 u3 = *(const float4*)(hp + 3 * HSTRIDE);
                ha[rep] = make_float4(u0.x + u1.x + u2.x + u3.x, u0.y + u1.y + u2.y + u3.y,
                                      u0.z + u1.z + u2.z + u3.z, u0.w + u1.w + u2.w + u3.w);
            }

            for (int rc = 0; rc < NSF; rc += 64) {
                #pragma unroll
                for (int rep = 0; rep < 8; ++rep) {
                    int o = rep * 16 + lr;
                    sm.p2.v1t[r4 + 0][o] = wa[rep].x; sm.p2.v1t[r4 + 1][o] = wa[rep].y;
                    sm.p2.v1t[r4 + 2][o] = wa[rep].z; sm.p2.v1t[r4 + 3][o] = wa[rep].w;
                }
                #pragma unroll
                for (int rep = 0; rep < 2; ++rep) {
                    int j = rep * 16 + lr;
                    sm.p2.hs[r4 + 0][j] = ha[rep].x; sm.p2.hs[r4 + 1][j] = ha[rep].y;
                    sm.p2.hs[r4 + 2][j] = ha[rep].z; sm.p2.hs[r4 + 3][j] = ha[rep].w;
                }
                __syncthreads();
                if (rc == 0) {
                    #pragma unroll
                    for (int rep = 0; rep < 8; ++rep)
                        wa[rep] = *(const float4*)(V1s + (size_t)(rep * 16 + lr) * NSF + 64 + r4);
                    #pragma unroll
                    for (int rep = 0; rep < 2; ++rep) {
                        const float* hp = Hp + (size_t)(rep * 16 + lr) * NSF + 64 + r4;
                        float4 u0 = *(const float4*)(hp);
                        float4 u1 = *(const float4*)(hp + HSTRIDE);
                        float4 u2 = *(const float4*)(hp + 2 * HSTRIDE);
                        float4 u3 = *(const float4*)(hp + 3 * HSTRIDE);
                        ha[rep] = make_float4(u0.x + u1.x + u2.x + u3.x, u0.y + u1.y + u2.y + u3.y,
                                              u0.z + u1.z + u2.z + u3.z, u0.w + u1.w + u2.w + u3.w);
                    }
                }
                #pragma unroll 8
                for (int r = 0; r < 64; ++r) {
                    float4 a = *(const float4*)&sm.p2.v1t[r][to4];
                    float4 h = *(const float4*)&sm.p2.hs[r][tj4];
                    acc[0][0] += a.x * h.x; acc[0][1] += a.x * h.y; acc[0][2] += a.x * h.z; acc[0][3] += a.x * h.w;
                    acc[1][0] += a.y * h.x; acc[1][1] += a.y * h.y; acc[1][2] += a.y * h.z; acc[1][3] += a.y * h.w;
                    acc[2][0] += a.z * h.x; acc[2][1] += a.z * h.y; acc[2][2] += a.z * h.z; acc[2][3] += a.z * h.w;
                    acc[3][0] += a.w * h.x; acc[3][1] += a.w * h.y; acc[3][2] += a.w * h.z; acc[3][3] += a.w * h.w;
                }
                __syncthreads();
            }

            #pragma unroll
            for (int ji = 0; ji < 4; ++ji) {
                int idx = jt * 32 + tj4 + ji;
                if (idx < nb) {
                    int   bki = sm.p2.bkx[tj4 + ji];
                    float w   = sm.p2.wjs[tj4 + ji];
                    *(float4*)(Ybuf + (size_t)bki * NOUT + ot * 128 + to4) =
                        make_float4(w * acc[0][ji], w * acc[1][ji], w * acc[2][ji], w * acc[3][ji]);
                }
            }
        }
    }
    grid.sync();

    // ---- Phase C: out[b][o] = sum_k Ybuf[b*8+k][o] -------------------------
    {
        int gid = blk * 256 + t;                 // 65536 threads == 65536 float4s
        const float4* yb = (const float4*)Ybuf + (size_t)(gid >> 8) * (NACT * 256) + (gid & 255);
        float4 r = yb[0];
        #pragma unroll
        for (int k = 1; k < NACT; ++k) {
            float4 u = yb[(size_t)k * 256];
            r.x += u.x; r.y += u.y; r.z += u.z; r.w += u.w;
        }
        ((float4*)out)[gid] = r;
    }
}

// ===========================================================================
// Fallback pipeline (proven R3/R4 structure) — used if coop launch fails.
// ===========================================================================
__global__ __launch_bounds__(256) void attn_topk(
    const float* __restrict__ q, const float* __restrict__ Wk,
    const float* __restrict__ bk, int* __restrict__ counts,
    int* __restrict__ list_bk, float* __restrict__ list_w)
{
    int b = blockIdx.x;
    int t = threadIdx.x;
    __shared__ float qs[NQ];
    __shared__ float att[NS];

    ((float4*)qs)[t] = ((const float4*)(q + (size_t)b * NQ))[t];
    __syncthreads();
    int sid = t >> 2, il = t & 3;
    const float* wrow = Wk + (size_t)sid * NQ + (il << 2);
    const float* qrow = qs + (il << 2);
    float acc = 0.f;
    #pragma unroll 8
    for (int i = 0; i < NQ; i += 16) {
        float4 w4 = *(const float4*)(wrow + i);
        float4 q4 = *(const float4*)(qrow + i);
        acc += w4.x * q4.x + w4.y * q4.y + w4.z * q4.z + w4.w * q4.w;
    }
    acc += __shfl_xor(acc, 1);
    acc += __shfl_xor(acc, 2);
    if (il == 0) att[sid] = acc + bk[sid];
    __syncthreads();

    if (t < 64) {
        float v = att[t];
        float top_v[NACT]; int top_i[NACT];
        #pragma unroll
        for (int k = 0; k < NACT; ++k) {
            float mv = v; int mi = t;
            #pragma unroll
            for (int off = 1; off < 64; off <<= 1) {
                float ov = __shfl_xor(mv, off);
                int   oi = __shfl_xor(mi, off);
                if (ov > mv || (ov == mv && oi < mi)) { mv = ov; mi = oi; }
            }
            top_v[k] = mv; top_i[k] = mi;
            if (t == mi) v = -INFINITY;
        }
        if (t == 0) {
            float m = top_v[0], den = 0.f, e[NACT];
            #pragma unroll
            for (int k = 0; k < NACT; ++k) { e[k] = expf(top_v[k] - m); den += e[k]; }
            float inv = 1.f / den;
            #pragma unroll
            for (int k = 0; k < NACT; ++k) {
                int s = top_i[k];
                int slot = atomicAdd(&counts[s], 1);
                if (slot < NSLOT) {
                    list_bk[s * NSLOT + slot] = b * NACT + k;
                    list_w[s * NSLOT + slot]  = e[k] * inv;
                }
            }
        }
    }
}

__global__ __launch_bounds__(256) void subnet_h_fb(
    const float* __restrict__ x, const float* __restrict__ V0,
    const int* __restrict__ counts, const int* __restrict__ list_bk,
    float* __restrict__ Hpart)
{
    int s  = blockIdx.x;
    int ic = blockIdx.y;          // i-chunk of 256
    int jt = blockIdx.z;
    int nb = counts[s]; if (nb > NSLOT) nb = NSLOT;
    if (jt * 32 >= nb) return;
    int t = threadIdx.x;

    __shared__ float v0t[64][129];
    __shared__ float xt[64][33];
    __shared__ int   bidx[32];

    if (t < 32) {
        int idx = jt * 32 + t;
        bidx[t] = (idx < nb) ? (list_bk[s * NSLOT + idx] >> 3) : 0;
    }
    __syncthreads();

    int i0 = ic * 256;
    const float* V0s = V0 + (size_t)s * NSF * NIN + i0;

    int lr  = t >> 4;
    int li4 = (t & 15) << 2;
    int to4 = (t & 31) << 2;
    int tj4 = (t >> 5) << 2;

    float4 va[8], vb[2];
    float acc[4][4] = {};

    #pragma unroll
    for (int rep = 0; rep < 8; ++rep)
        va[rep] = *(const float4*)(V0s + (size_t)(rep * 16 + lr) * NIN + li4);
    #pragma unroll
    for (int rep = 0; rep < 2; ++rep)
        vb[rep] = *(const float4*)(x + (size_t)bidx[rep * 16 + lr] * NIN + i0 + li4);

    for (int ks = 0; ks < 256; ks += 64) {
        #pragma unroll
        for (int rep = 0; rep < 8; ++rep) {
            int r = rep * 16 + lr;
            v0t[li4 + 0][r] = va[rep].x; v0t[li4 + 1][r] = va[rep].y;
            v0t[li4 + 2][r] = va[rep].z; v0t[li4 + 3][r] = va[rep].w;
        }
        #pragma unroll
        for (int rep = 0; rep < 2; ++rep) {
            int j = rep * 16 + lr;
            xt[li4 + 0][j] = vb[rep].x; xt[li4 + 1][j] = vb[rep].y;
            xt[li4 + 2][j] = vb[rep].z; xt[li4 + 3][j] = vb[rep].w;
        }
        __syncthreads();
        if (ks < 192) {
            int kn = ks + 64;
            #pragma unroll
            for (int rep = 0; rep < 8; ++rep)
                va[rep] = *(const float4*)(V0s + (size_t)(rep * 16 + lr) * NIN + kn + li4);
            #pragma unroll
            for (int rep = 0; rep < 2; ++rep)
                vb[rep] = *(const float4*)(x + (size_t)bidx[rep * 16 + lr] * NIN + i0 + kn + li4);
        }
        #pragma unroll 8
        for (int i = 0; i < 64; ++i) {
            float4 a = *(const float4*)&v0t[i][to4];
            float4 h = *(const float4*)&xt[i][tj4];
            acc[0][0] += a.x * h.x; acc[0][1] += a.x * h.y; acc[0][2] += a.x * h.z; acc[0][3] += a.x * h.w;
            acc[1][0] += a.y * h.x; acc[1][1] += a.y * h.y; acc[1][2] += a.y * h.z; acc[1][3] += a.y * h.w;
            acc[2][0] += a.z * h.x; acc[2][1] += a.z * h.y; acc[2][2] += a.z * h.z; acc[2][3] += a.z * h.w;
            acc[3][0] += a.w * h.x; acc[3][1] += a.w * h.y; acc[3][2] += a.w * h.z; acc[3][3] += a.w * h.w;
        }
        __syncthreads();
    }

    float* Hp = Hpart + ((size_t)(ic * NS + s) * NSLOT + jt * 32) * NSF;
    #pragma unroll
    for (int ji = 0; ji < 4; ++ji) {
        *(float4*)(Hp + (size_t)(tj4 + ji) * NSF + to4) =
            make_float4(acc[0][ji], acc[1][ji], acc[2][ji], acc[3][ji]);
    }
}

__global__ __launch_bounds__(256) void subnet_out_fb(
    const float* __restrict__ V1, const int* __restrict__ counts,
    const int* __restrict__ list_bk, const float* __restrict__ list_w,
    const float* __restrict__ Hpart, float* __restrict__ Ybuf)
{
    int s  = blockIdx.x;
    int ot = blockIdx.y;
    int jt = blockIdx.z;
    int nb = counts[s]; if (nb > NSLOT) nb = NSLOT;
    if (jt * 32 >= nb) return;
    int t = threadIdx.x;

    __shared__ float v1t[64][129];
    __shared__ float hs[64][33];
    __shared__ int   bkx[32];
    __shared__ float wjs[32];

    if (t < 32) {
        int idx = jt * 32 + t;
        bool v = idx < nb;
        bkx[t] = v ? list_bk[s * NSLOT + idx] : 0;
        wjs[t] = v ? list_w[s * NSLOT + idx] : 0.f;
    }

    const float* V1s = V1 + (size_t)s * NOUT * NSF + (size_t)ot * 128 * NSF;
    const float* Hp  = Hpart + ((size_t)s * NSLOT + jt * 32) * NSF;
    const size_t HSTRIDE = (size_t)NS * NSLOT * NSF;

    int lr  = t >> 4;
    int r4  = (t & 15) << 2;
    int to4 = (t & 31) << 2;
    int tj4 = (t >> 5) << 2;

    float4 wa[8], ha[2];
    float acc[4][4] = {};

    #pragma unroll
    for (int rep = 0; rep < 8; ++rep)
        wa[rep] = *(const float4*)(V1s + (size_t)(rep * 16 + lr) * NSF + r4);
    #pragma unroll
    for (int rep = 0; rep < 2; ++rep) {
        const float* hp = Hp + (size_t)(rep * 16 + lr) * NSF + r4;
        float4 u0 = *(const float4*)(hp);
        float4 u1 = *(const float4*)(hp + HSTRIDE);
        float4 u2 = *(const float4*)(hp + 2 * HSTRIDE);
        float4 u3 = *(const float4*)(hp + 3 * HSTRIDE);
        ha[rep] = make_float4(u0.x + u1.x + u2.x + u3.x, u0.y + u1.y + u2.y + u3.y,
                              u0.z + u1.z + u2.z + u3.z, u0.w + u1.w + u2.w + u3.w);
    }

    for (int rc = 0; rc < NSF; rc += 64) {
        #pragma unroll
        for (int rep = 0; rep < 8; ++rep) {
            int o = rep * 16 + lr;
            v1t[r4 + 0][o] = wa[rep].x; v1t[r4 + 1][o] = wa[rep].y;
            v1t[r4 + 2][o] = wa[rep].z; v1t[r4 + 3][o] = wa[rep].w;
        }
        #pragma unroll
        for (int rep = 0; rep < 2; ++rep) {
            int j = rep * 16 + lr;
            hs[r4 + 0][j] = ha[rep].x; hs[r4 + 1][j] = ha[rep].y;
            hs[r4 + 2][j] = ha[rep].z; hs[r4 + 3][j] = ha[rep].w;
        }
        __syncthreads();
        if (rc == 0) {
            #pragma unroll
            for (int rep = 0; rep < 8; ++rep)
                wa[rep] = *(const float4*)(V1s + (size_t)(rep * 16 + lr) * NSF + 64 + r4);
            #pragma unroll
            for (int rep = 0; rep < 2; ++rep) {
                const float* hp = Hp + (size_t)(rep * 16 + lr) * NSF + 64 + r4;
                float4 u0 = *(const float4*)(hp);
                float4 u1 = *(const float4*)(hp + HSTRIDE);
                float4 u2 = *(const float4*)(hp + 2 * HSTRIDE);
                float4 u3 = *(const float4*)(hp + 3 * HSTRIDE);
                ha[rep] = make_float4(u0.x + u1.x + u2.x + u3.x, u0.y + u1.y + u2.y + u3.y,
                                      u0.z + u1.z + u2.z + u3.z, u0.w + u1.w + u2.w + u3.w);
            }
        }
        #pragma unroll 8
        for (int r = 0; r < 64; ++r) {
            float4 a = *(const float4*)&v1t[r][to4];
            float4 h = *(const float4*)&hs[r][tj4];
            acc[0][0] += a.x * h.x; acc[0][1] += a.x * h.y; acc[0][2] += a.x * h.z; acc[0][3] += a.x * h.w;
            acc[1][0] += a.y * h.x; acc[1][1] += a.y * h.y; acc[1][2] += a.y * h.z; acc[1][3] += a.y * h.w;
            acc[2][0] += a.z * h.x; acc[2][1] += a.z * h.y; acc[2][2] += a.z * h.z; acc[2][3] += a.z * h.w;
            acc[3][0] += a.w * h.x; acc[3][1] += a.w * h.y; acc[3][2] += a.w * h.z; acc[3][3] += a.w * h.w;
        }
        __syncthreads();
    }

    #pragma unroll
    for (int ji = 0; ji < 4; ++ji) {
        int idx = jt * 32 + tj4 + ji;
        if (idx < nb) {
            int   bki = bkx[tj4 + ji];
            float w   = wjs[tj4 + ji];
            *(float4*)(Ybuf + (size_t)bki * NOUT + ot * 128 + to4) =
                make_float4(w * acc[0][ji], w * acc[1][ji], w * acc[2][ji], w * acc[3][ji]);
        }
    }
}

__global__ __launch_bounds__(256) void reduce_out_fb(
    const float* __restrict__ Ybuf, float* __restrict__ out)
{
    int gid = blockIdx.x * 256 + threadIdx.x;
    const float4* yb = (const float4*)Ybuf + (size_t)(gid >> 8) * (NACT * 256) + (gid & 255);
    float4 r = yb[0];
    #pragma unroll
    for (int k = 1; k < NACT; ++k) {
        float4 u = yb[(size_t)k * 256];
        r.x += u.x; r.y += u.y; r.z += u.z; r.w += u.w;
    }
    ((float4*)out)[gid] = r;
}

// ---------------------------------------------------------------------------
extern "C" void kernel_launch(void* const* d_in, const int* in_sizes, int n_in,
                              void* d_out, int out_size, void* d_ws, size_t ws_size,
                              hipStream_t stream)
{
    const float* x  = (const float*)d_in[0];
    const float* q  = (const float*)d_in[1];
    const float* Wk = (const float*)d_in[2];
    const float* bk = (const float*)d_in[3];
    const float* V0 = (const float*)d_in[4];
    const float* V1 = (const float*)d_in[5];
    float* out = (float*)d_out;

    char* ws = (char*)d_ws;
    int*   counts  = (int*)(ws + WS_COUNTS);
    int*   list_bk = (int*)(ws + WS_LISTBK);
    float* list_w  = (float*)(ws + WS_LISTW);
    float* Ybuf    = (float*)(ws + WS_Y);
    float* Hpart   = (float*)(ws + WS_H);

    hipMemsetAsync(counts, 0, 1024, stream);

    void* args[] = { (void*)&x, (void*)&q, (void*)&Wk, (void*)&bk,
                     (void*)&V0, (void*)&V1, (void*)&counts, (void*)&list_bk,
                     (void*)&list_w, (void*)&Ybuf, (void*)&Hpart, (void*)&out };

    hipError_t err = hipLaunchCooperativeKernel((void*)fused_all, dim3(NBLK),
                                                dim3(256), args, 0, stream);
    if (err != hipSuccess) {
        // Fallback: proven 4-kernel pipeline (same math, same workspace).
        attn_topk<<<dim3(NB), 256, 0, stream>>>(q, Wk, bk, counts, list_bk, list_w);
        subnet_h_fb<<<dim3(NS, 4, 2), 256, 0, stream>>>(x, V0, counts, list_bk, Hpart);
        subnet_out_fb<<<dim3(NS, 8, 2), 256, 0, stream>>>(V1, counts, list_bk, list_w, Hpart, Ybuf);
        reduce_out_fb<<<dim3(NB), 256, 0, stream>>>(Ybuf, out);
    }
}

// Round 7
// 191.153 us; speedup vs baseline: 1.5416x; 1.5416x over previous
//
#include <hip/hip_runtime.h>
#include <math.h>

// Problem constants
#define NB   256   // batch
#define NIN  1024  // in_features
#define NOUT 1024  // out_features
#define NSF  128   // sub_features (rank)
#define NQ   1024  // q_features
#define NS   64    // num subnets
#define NACT 8     // top-k active
#define NSLOT 64   // per-subnet slot capacity (nb ~ Binom: mean 32, max ~50)
#define NIC  4     // i-chunks in B1 (chunk = 256)

// Workspace layout (bytes). Total ~16.9 MB.
#define WS_COUNTS 0          // 64 ints
#define WS_LISTBK 1024       // int  [64][64]
#define WS_LISTW  17408      // float[64][64]
#define WS_ATT    33792      // float[256][64]
#define WS_Y      99328      // float[2048][1024] Ybuf[b*8+k][o]            (8.39 MB)
#define WS_H      8487936    // float[4][64][64][128] Hpart[ic][s][slot][r] (8.39 MB)

// ---------------------------------------------------------------------------
// Kernel A1: att[b][s] = q[b] . Wk[s] + bk[s].  Tiled 8b x 8s per block,
// grid (32,8) = 256 blocks. Per-(b,s) dot split over 4 lanes. Cuts Wk
// traffic 67 MB -> 16 MB vs row-per-block, keeps 256 independent blocks.
// ---------------------------------------------------------------------------
__global__ __launch_bounds__(256) void attn_gemm(
    const float* __restrict__ q, const float* __restrict__ Wk,
    const float* __restrict__ bk, float* __restrict__ att)
{
    int bt = blockIdx.x;        // row tile (8 rows)
    int st = blockIdx.y;        // col tile (8 subnets)
    int t  = threadIdx.x;
    int r  = t >> 5;            // 0..7
    int c  = (t >> 2) & 7;      // 0..7
    int il = t & 3;

    const float4* qp = (const float4*)(q  + (size_t)(bt * 8 + r) * NQ) + il;
    const float4* wp = (const float4*)(Wk + (size_t)(st * 8 + c) * NQ) + il;
    float acc = 0.f;
    #pragma unroll 8
    for (int k = 0; k < 64; ++k) {
        float4 a = qp[k * 4];
        float4 w = wp[k * 4];
        acc += a.x * w.x + a.y * w.y + a.z * w.z + a.w * w.w;
    }
    acc += __shfl_xor(acc, 1);
    acc += __shfl_xor(acc, 2);
    if (il == 0)
        att[(size_t)(bt * 8 + r) * NS + st * 8 + c] = acc + bk[st * 8 + c];
}

// ---------------------------------------------------------------------------
// Kernel A2: per-row top-8 (butterfly argmax x8) + softmax + append to
// per-subnet lists. 256 blocks x 64 threads (one wave).
// ---------------------------------------------------------------------------
__global__ __launch_bounds__(64) void topk_k(
    const float* __restrict__ att, int* __restrict__ counts,
    int* __restrict__ list_bk, float* __restrict__ list_w)
{
    int b = blockIdx.x;
    int t = threadIdx.x;   // 0..63 = subnet
    float v = att[(size_t)b * NS + t];
    float top_v[NACT]; int top_i[NACT];
    #pragma unroll
    for (int k = 0; k < NACT; ++k) {
        float mv = v; int mi = t;
        #pragma unroll
        for (int off = 1; off < 64; off <<= 1) {
            float ov = __shfl_xor(mv, off);
            int   oi = __shfl_xor(mi, off);
            if (ov > mv || (ov == mv && oi < mi)) { mv = ov; mi = oi; }
        }
        top_v[k] = mv; top_i[k] = mi;
        if (t == mi) v = -INFINITY;
    }
    if (t == 0) {
        float m = top_v[0], den = 0.f, e[NACT];
        #pragma unroll
        for (int k = 0; k < NACT; ++k) { e[k] = expf(top_v[k] - m); den += e[k]; }
        float inv = 1.f / den;
        #pragma unroll
        for (int k = 0; k < NACT; ++k) {
            int s = top_i[k];
            int slot = atomicAdd(&counts[s], 1);
            if (slot < NSLOT) {
                list_bk[s * NSLOT + slot] = b * NACT + k;
                list_w[s * NSLOT + slot]  = e[k] * inv;
            }
        }
    }
}

// ---------------------------------------------------------------------------
// Kernel B1: Hpart[ic][s][j][r] = V0[s, r, ic*256:+256] . x[b_j, same]
// grid (64 s, rt2 x ic4, jt2). Tile 64r x 32j x 256i; thread = 2r x 4j
// (to = t>>3: 8 lanes share V0 float4 -> broadcast coalesce).
// Only x is staged in LDS (18 KB); V0 streams global->reg->FMA with NO
// barrier in the inner loop. xs pad 36 keeps float4 align + bcast reads.
// ---------------------------------------------------------------------------
__global__ __launch_bounds__(256) void subnet_h(
    const float* __restrict__ x, const float* __restrict__ V0,
    const int* __restrict__ counts, const int* __restrict__ list_bk,
    float* __restrict__ Hpart)
{
    int s  = blockIdx.x;
    int rt = blockIdx.y & 1;       // r-tile of 64
    int ic = blockIdx.y >> 1;      // i-chunk of 256
    int jt = blockIdx.z;
    int nb = counts[s]; if (nb > NSLOT) nb = NSLOT;
    if (jt * 32 >= nb) return;
    int t = threadIdx.x;

    __shared__ float xs[128][36];   // [i][j], pad 36 (16B-aligned rows)
    __shared__ int   bidx[32];

    if (t < 32) {
        int idx = jt * 32 + t;
        bidx[t] = (idx < nb) ? (list_bk[s * NSLOT + idx] >> 3) : 0;
    }
    __syncthreads();

    int lj = t >> 3;                // stage row j 0..31
    int lc = t & 7;                 // 0..7
    const float4* xrow = (const float4*)(x + (size_t)bidx[lj] * NIN + ic * 256);

    int tr = t >> 3;                // r-pair 0..31
    int tj = t & 7;                 // j-quad
    int r0 = rt * 64 + tr * 2;
    const float4* v0a = (const float4*)(V0 + ((size_t)s * NSF + r0) * NIN + ic * 256);
    const float4* v0b = v0a + (NIN / 4);

    float acc[2][4] = {};
    float4 pf[4];
    #pragma unroll
    for (int k = 0; k < 4; ++k) pf[k] = xrow[lc + 8 * k];

    for (int ch = 0; ch < 2; ++ch) {
        #pragma unroll
        for (int k = 0; k < 4; ++k) {
            int i = (lc + 8 * k) * 4;
            xs[i + 0][lj] = pf[k].x; xs[i + 1][lj] = pf[k].y;
            xs[i + 2][lj] = pf[k].z; xs[i + 3][lj] = pf[k].w;
        }
        __syncthreads();
        if (ch == 0) {
            #pragma unroll
            for (int k = 0; k < 4; ++k) pf[k] = xrow[32 + lc + 8 * k];
        }
        const float4* va = v0a + ch * 32;
        const float4* vb = v0b + ch * 32;
        #pragma unroll 4
        for (int i4 = 0; i4 < 32; ++i4) {
            float4 a = va[i4];
            float4 b = vb[i4];
            const float* xc = &xs[i4 * 4][tj << 2];
            float4 h0 = *(const float4*)(xc);
            float4 h1 = *(const float4*)(xc + 36);
            float4 h2 = *(const float4*)(xc + 72);
            float4 h3 = *(const float4*)(xc + 108);
            acc[0][0] += a.x * h0.x; acc[0][1] += a.x * h0.y; acc[0][2] += a.x * h0.z; acc[0][3] += a.x * h0.w;
            acc[1][0] += b.x * h0.x; acc[1][1] += b.x * h0.y; acc[1][2] += b.x * h0.z; acc[1][3] += b.x * h0.w;
            acc[0][0] += a.y * h1.x; acc[0][1] += a.y * h1.y; acc[0][2] += a.y * h1.z; acc[0][3] += a.y * h1.w;
            acc[1][0] += b.y * h1.x; acc[1][1] += b.y * h1.y; acc[1][2] += b.y * h1.z; acc[1][3] += b.y * h1.w;
            acc[0][0] += a.z * h2.x; acc[0][1] += a.z * h2.y; acc[0][2] += a.z * h2.z; acc[0][3] += a.z * h2.w;
            acc[1][0] += b.z * h2.x; acc[1][1] += b.z * h2.y; acc[1][2] += b.z * h2.z; acc[1][3] += b.z * h2.w;
            acc[0][0] += a.w * h3.x; acc[0][1] += a.w * h3.y; acc[0][2] += a.w * h3.z; acc[0][3] += a.w * h3.w;
            acc[1][0] += b.w * h3.x; acc[1][1] += b.w * h3.y; acc[1][2] += b.w * h3.z; acc[1][3] += b.w * h3.w;
        }
        if (ch == 0) __syncthreads();
    }

    float* Hp = Hpart + ((size_t)(ic * NS + s) * NSLOT + jt * 32 + (tj << 2)) * NSF + r0;
    #pragma unroll
    for (int ji = 0; ji < 4; ++ji)
        *(float2*)(Hp + (size_t)ji * NSF) = make_float2(acc[0][ji], acc[1][ji]);
}

// ---------------------------------------------------------------------------
// Kernel B2: Y[o,j] = V1[s,o,:] . (sum_ic Hpart)[s,j,:];
// Ybuf[bk_j][o] = w_j * Y. grid (64 s, 16 ot, 2 jt). Tile 64o x 32j;
// thread = 2o x 4j. H staged ONCE (18 KB, 4 partials folded), then a
// completely barrier-free K-loop streaming V1 global->reg->FMA.
// ---------------------------------------------------------------------------
__global__ __launch_bounds__(256) void subnet_out(
    const float* __restrict__ V1, const int* __restrict__ counts,
    const int* __restrict__ list_bk, const float* __restrict__ list_w,
    const float* __restrict__ Hpart, float* __restrict__ Ybuf)
{
    int s  = blockIdx.x;
    int ot = blockIdx.y;           // o-tile of 64
    int jt = blockIdx.z;
    int nb = counts[s]; if (nb > NSLOT) nb = NSLOT;
    if (jt * 32 >= nb) return;
    int t = threadIdx.x;

    __shared__ float hs[128][36];  // [r][j]
    __shared__ int   bkx[32];
    __shared__ float wjs[32];

    if (t < 32) {
        int idx = jt * 32 + t;
        bool v = idx < nb;
        bkx[t] = v ? list_bk[s * NSLOT + idx] : 0;
        wjs[t] = v ? list_w[s * NSLOT + idx] : 0.f;
    }

    // stage hs[r][j] = sum of 4 i-chunk partials (transposed)
    {
        int lj  = t >> 3;          // j 0..31
        int lr4 = (t & 7) * 4;     // r base
        const float* Hp = Hpart + ((size_t)s * NSLOT + jt * 32 + lj) * NSF + lr4;
        const size_t HS = (size_t)NS * NSLOT * NSF;
        #pragma unroll
        for (int rep = 0; rep < 4; ++rep) {
            const float* hp = Hp + rep * 32;
            float4 u0 = *(const float4*)(hp);
            float4 u1 = *(const float4*)(hp + HS);
            float4 u2 = *(const float4*)(hp + 2 * HS);
            float4 u3 = *(const float4*)(hp + 3 * HS);
            int r = lr4 + rep * 32;
            hs[r + 0][lj] = u0.x + u1.x + u2.x + u3.x;
            hs[r + 1][lj] = u0.y + u1.y + u2.y + u3.y;
            hs[r + 2][lj] = u0.z + u1.z + u2.z + u3.z;
            hs[r + 3][lj] = u0.w + u1.w + u2.w + u3.w;
        }
    }
    __syncthreads();

    int to = t >> 3;               // o-pair 0..31
    int tj = t & 7;                // j-quad
    int o0 = ot * 64 + to * 2;
    const float4* r0p = (const float4*)(V1 + ((size_t)s * NOUT + o0) * NSF);
    const float4* r1p = r0p + (NSF / 4);
    float acc[2][4] = {};

    #pragma unroll 4
    for (int r4 = 0; r4 < 32; ++r4) {
        float4 a = r0p[r4];
        float4 b = r1p[r4];
        const float* hc = &hs[r4 * 4][tj << 2];
        float4 h0 = *(const float4*)(hc);
        float4 h1 = *(const float4*)(hc + 36);
        float4 h2 = *(const float4*)(hc + 72);
        float4 h3 = *(const float4*)(hc + 108);
        acc[0][0] += a.x * h0.x; acc[0][1] += a.x * h0.y; acc[0][2] += a.x * h0.z; acc[0][3] += a.x * h0.w;
        acc[1][0] += b.x * h0.x; acc[1][1] += b.x * h0.y; acc[1][2] += b.x * h0.z; acc[1][3] += b.x * h0.w;
        acc[0][0] += a.y * h1.x; acc[0][1] += a.y * h1.y; acc[0][2] += a.y * h1.z; acc[0][3] += a.y * h1.w;
        acc[1][0] += b.y * h1.x; acc[1][1] += b.y * h1.y; acc[1][2] += b.y * h1.z; acc[1][3] += b.y * h1.w;
        acc[0][0] += a.z * h2.x; acc[0][1] += a.z * h2.y; acc[0][2] += a.z * h2.z; acc[0][3] += a.z * h2.w;
        acc[1][0] += b.z * h2.x; acc[1][1] += b.z * h2.y; acc[1][2] += b.z * h2.z; acc[1][3] += b.z * h2.w;
        acc[0][0] += a.w * h3.x; acc[0][1] += a.w * h3.y; acc[0][2] += a.w * h3.z; acc[0][3] += a.w * h3.w;
        acc[1][0] += b.w * h3.x; acc[1][1] += b.w * h3.y; acc[1][2] += b.w * h3.z; acc[1][3] += b.w * h3.w;
    }

    #pragma unroll
    for (int ji = 0; ji < 4; ++ji) {
        int sl  = (tj << 2) + ji;
        int idx = jt * 32 + sl;
        if (idx < nb) {
            float w = wjs[sl];
            *(float2*)(Ybuf + (size_t)bkx[sl] * NOUT + o0) =
                make_float2(w * acc[0][ji], w * acc[1][ji]);
        }
    }
}

// ---------------------------------------------------------------------------
// Kernel C: out[b][o] = sum_k Ybuf[b*8+k][o]. 256 blocks x 256 thr, float4.
// ---------------------------------------------------------------------------
__global__ __launch_bounds__(256) void reduce_out(
    const float* __restrict__ Ybuf, float* __restrict__ out)
{
    int gid = blockIdx.x * 256 + threadIdx.x;
    const float4* yb = (const float4*)Ybuf + (size_t)(gid >> 8) * (NACT * 256) + (gid & 255);
    float4 r = yb[0];
    #pragma unroll
    for (int k = 1; k < NACT; ++k) {
        float4 u = yb[(size_t)k * 256];
        r.x += u.x; r.y += u.y; r.z += u.z; r.w += u.w;
    }
    ((float4*)out)[gid] = r;
}

// ---------------------------------------------------------------------------
extern "C" void kernel_launch(void* const* d_in, const int* in_sizes, int n_in,
                              void* d_out, int out_size, void* d_ws, size_t ws_size,
                              hipStream_t stream)
{
    const float* x  = (const float*)d_in[0];
    const float* q  = (const float*)d_in[1];
    const float* Wk = (const float*)d_in[2];
    const float* bk = (const float*)d_in[3];
    const float* V0 = (const float*)d_in[4];
    const float* V1 = (const float*)d_in[5];
    float* out = (float*)d_out;

    char* ws = (char*)d_ws;
    int*   counts  = (int*)(ws + WS_COUNTS);
    int*   list_bk = (int*)(ws + WS_LISTBK);
    float* list_w  = (float*)(ws + WS_LISTW);
    float* att     = (float*)(ws + WS_ATT);
    float* Ybuf    = (float*)(ws + WS_Y);
    float* Hpart   = (float*)(ws + WS_H);

    hipMemsetAsync(counts, 0, 1024, stream);

    attn_gemm<<<dim3(32, 8), 256, 0, stream>>>(q, Wk, bk, att);
    topk_k<<<dim3(NB), 64, 0, stream>>>(att, counts, list_bk, list_w);
    subnet_h<<<dim3(NS, 8, 2), 256, 0, stream>>>(x, V0, counts, list_bk, Hpart);
    subnet_out<<<dim3(NS, 16, 2), 256, 0, stream>>>(V1, counts, list_bk, list_w, Hpart, Ybuf);
    reduce_out<<<dim3(NB), 256, 0, stream>>>(Ybuf, out);
}